// Round 5
// baseline (188.548 us; speedup 1.0000x reference)
//
#include <hip/hip_runtime.h>
#include <math.h>

#define EPS 1e-7f
#define REG_MAX 16
#define A_DIM 8400

// d_ws layout:
//   [0]          int    ticket      (zeroed by 4-byte memset each launch)
//   [16..]       float4 partials[nb] : (liou, dfl, nfg, unused) per block

__global__ __launch_bounds__(256) void bbox_loss_fused(
    const float* __restrict__ pred_dist,      // (B,A,64)
    const float* __restrict__ pred_bboxes,    // (B,A,4)
    const float* __restrict__ anchor_points,  // (A,2)
    const float* __restrict__ target_bboxes,  // (B,A,4)
    const float* __restrict__ target_scores,  // (B,A,80)
    const int*   __restrict__ fg_mask,        // (B,A) int32
    const float* __restrict__ tss,
    int*   __restrict__ ticket,
    float4* __restrict__ partials,
    float* __restrict__ out,
    int total, int nb)
{
    __shared__ int s_idx[256];
    __shared__ int s_wtot[4];
    __shared__ int s_woff[4];
    __shared__ int s_cnt;

    const int tid  = threadIdx.x;
    const int i0   = blockIdx.x * 256 + tid;
    const int wave = tid >> 6;
    const int lane = tid & 63;

    // ---- block-local stream compaction into LDS ----
    const bool fg = (i0 < total) && (fg_mask[i0] != 0);
    const unsigned long long ball = __ballot(fg);
    const int pre = __popcll(ball & ((1ull << lane) - 1ull));
    if (lane == 0) s_wtot[wave] = __popcll(ball);
    __syncthreads();
    if (tid == 0) {
        int off = 0;
        #pragma unroll
        for (int k = 0; k < 4; ++k) { s_woff[k] = off; off += s_wtot[k]; }
        s_cnt = off;
    }
    __syncthreads();
    if (fg) s_idx[s_woff[wave] + pre] = i0;
    __syncthreads();
    const int cnt = s_cnt;

    // ---- cooperative processing: 16 lanes per fg item ----
    float liou = 0.f, ldfl = 0.f;

    const int g  = tid >> 4;   // group 0..15
    const int gl = tid & 15;   // lane within group
    const int q  = gl >> 2;    // side 0..3 (l,t,r,b)
    const int ql = gl & 3;     // lane within quad

    for (int j = g; j < cnt; j += 16) {
        const int i = s_idx[j];
        const int a = i % A_DIM;

        // weight = sum of 80 class scores, split across 16 lanes (20 float4s)
        const float4* ts4 = (const float4*)(target_scores + (size_t)i * 80);
        float4 v = ts4[gl];
        float w = v.x + v.y + v.z + v.w;
        if (gl < 4) { float4 u = ts4[16 + gl]; w += u.x + u.y + u.z + u.w; }
        #pragma unroll
        for (int off = 8; off >= 1; off >>= 1) w += __shfl_xor(w, off);

        const float4 tb = *(const float4*)(target_bboxes + (size_t)i * 4);
        const float ax = anchor_points[2 * a];
        const float ay = anchor_points[2 * a + 1];

        // ---- DFL: quad q owns side q's 16-bin softmax, 4 bins per lane ----
        float tq = (q == 0) ? (ax - tb.x) : (q == 1) ? (ay - tb.y)
                 : (q == 2) ? (tb.z - ax) : (tb.w - ay);
        tq = fminf(fmaxf(tq, 0.f), (float)(REG_MAX - 1) - 0.01f);

        const float4 x4 = ((const float4*)(pred_dist + (size_t)i * 64))[q * 4 + ql];
        float m = fmaxf(fmaxf(x4.x, x4.y), fmaxf(x4.z, x4.w));
        m = fmaxf(m, __shfl_xor(m, 1));
        m = fmaxf(m, __shfl_xor(m, 2));
        float se = __expf(x4.x - m) + __expf(x4.y - m)
                 + __expf(x4.z - m) + __expf(x4.w - m);
        se += __shfl_xor(se, 1);
        se += __shfl_xor(se, 2);
        const float lse = m + __logf(se);

        const int   tl = (int)tq;
        const int   tr = min(tl + 1, REG_MAX - 1);
        const float wl = (float)(tl + 1) - tq;
        const float wr = 1.f - wl;
        const int base = ql * 4;
        float s = 0.f;
        int r = tl - base;
        if (r >= 0 && r < 4) s += wl * (r == 0 ? x4.x : r == 1 ? x4.y : r == 2 ? x4.z : x4.w);
        r = tr - base;
        if (r >= 0 && r < 4) s += wr * (r == 0 ? x4.x : r == 1 ? x4.y : r == 2 ? x4.z : x4.w);
        s += __shfl_xor(s, 1);
        s += __shfl_xor(s, 2);
        if (ql == 0) ldfl += lse - s;   // ce_l*wl + ce_r*wr for this side

        // ---- CIoU on the group leader ----
        if (gl == 0) {
            const float4 pb = *(const float4*)(pred_bboxes + (size_t)i * 4);
            const float x11 = pb.x, y11 = pb.y, x21 = pb.z, y21 = pb.w;
            const float x12 = tb.x, y12 = tb.y, x22 = tb.z, y22 = tb.w;
            const float iw = fmaxf(fminf(x21, x22) - fmaxf(x11, x12), 0.f);
            const float ih = fmaxf(fminf(y21, y22) - fmaxf(y11, y12), 0.f);
            const float inter = iw * ih;
            const float w1 = x21 - x11, h1 = y21 - y11;
            const float w2 = x22 - x12, h2 = y22 - y12;
            const float uni = w1 * h1 + w2 * h2 - inter + EPS;
            const float iou = inter / uni;
            const float cw = fmaxf(x21, x22) - fminf(x11, x12);
            const float ch = fmaxf(y21, y22) - fminf(y11, y12);
            const float c2 = cw * cw + ch * ch + EPS;
            const float dx = x11 + x21 - x12 - x22;
            const float dy = y11 + y21 - y12 - y22;
            const float rho2 = (dx * dx + dy * dy) * 0.25f;
            const float dang = atanf(w1 / (h1 + EPS)) - atanf(w2 / (h2 + EPS));
            const float vv = (4.f / (float)(M_PI * M_PI)) * dang * dang;
            const float alpha = vv / (1.f - iou + vv + EPS);
            const float ciou = iou - (rho2 / c2 + vv * alpha);
            liou += (1.f - ciou) * w;
        }
    }

    // ---- block reduction -> packed partial slot (one 16B store, no atomics) ----
    #pragma unroll
    for (int off = 32; off >= 1; off >>= 1) {
        liou += __shfl_down(liou, off);
        ldfl += __shfl_down(ldfl, off);
    }
    __shared__ float r0[4], r1[4];
    if (lane == 0) { r0[wave] = liou; r1[wave] = ldfl; }
    __syncthreads();

    __shared__ bool s_last;
    if (tid == 0) {
        float4 p;
        p.x = r0[0] + r0[1] + r0[2] + r0[3];
        p.y = r1[0] + r1[1] + r1[2] + r1[3];
        p.z = (float)cnt;
        p.w = 0.f;
        partials[blockIdx.x] = p;
        __threadfence();                       // partial visible before ticket
        s_last = (atomicAdd(ticket, 1) == nb - 1);
    }
    __syncthreads();

    // ---- last block folds all partials and writes the output ----
    if (s_last) {
        float a = 0.f, b = 0.f, c = 0.f;
        for (int k = tid; k < nb; k += 256) {
            const float4 p = partials[k];      // device-coherent: written before ticket+fence
            a += p.x; b += p.y; c += p.z;
        }
        #pragma unroll
        for (int off = 32; off >= 1; off >>= 1) {
            a += __shfl_down(a, off);
            b += __shfl_down(b, off);
            c += __shfl_down(c, off);
        }
        if (lane == 0) { r0[wave] = a; r1[wave] = b; if (wave == 0) s_wtot[0] = 0; }
        __shared__ float r2[4];
        if (lane == 0) r2[wave] = c;
        __syncthreads();
        if (tid == 0) {
            const float A  = r0[0] + r0[1] + r0[2] + r0[3];
            const float Bs = r1[0] + r1[1] + r1[2] + r1[3];
            const float C  = r2[0] + r2[1] + r2[2] + r2[3];
            out[0] = A / tss[0];
            out[1] = Bs / fmaxf(C * 4.f, 1.f);
        }
    }
}

extern "C" void kernel_launch(void* const* d_in, const int* in_sizes, int n_in,
                              void* d_out, int out_size, void* d_ws, size_t ws_size,
                              hipStream_t stream) {
    const float* pred_dist     = (const float*)d_in[0];
    const float* pred_bboxes   = (const float*)d_in[1];
    const float* anchor_points = (const float*)d_in[2];
    const float* target_bboxes = (const float*)d_in[3];
    const float* target_scores = (const float*)d_in[4];
    const float* tss           = (const float*)d_in[5];
    const int*   fg_mask       = (const int*)d_in[6];
    float* out = (float*)d_out;

    int*    ticket   = (int*)d_ws;
    float4* partials = (float4*)((char*)d_ws + 16);

    const int total = in_sizes[6];               // B*A = 268800
    const int nb = (total + 255) / 256;          // 1050

    hipMemsetAsync(ticket, 0, sizeof(int), stream);
    bbox_loss_fused<<<nb, 256, 0, stream>>>(pred_dist, pred_bboxes, anchor_points,
                                            target_bboxes, target_scores, fg_mask,
                                            tss, ticket, partials, out, total, nb);
}

// Round 6
// 168.283 us; speedup vs baseline: 1.1204x; 1.1204x over previous
//
#include <hip/hip_runtime.h>
#include <math.h>

#define EPS 1e-7f
#define REG_MAX 16
#define A_DIM 8400

// d_ws layout: float4 partials[nb] : (liou, dfl, nfg, unused) per block.
// Every slot written unconditionally -> no memset, no atomics, no fences.

__global__ __launch_bounds__(256) void bbox_loss_fused(
    const float* __restrict__ pred_dist,      // (B,A,64)
    const float* __restrict__ pred_bboxes,    // (B,A,4)
    const float* __restrict__ anchor_points,  // (A,2)
    const float* __restrict__ target_bboxes,  // (B,A,4)
    const float* __restrict__ target_scores,  // (B,A,80)
    const int*   __restrict__ fg_mask,        // (B,A) int32
    float4* __restrict__ partials,
    int total)
{
    __shared__ int s_idx[256];
    __shared__ int s_wtot[4];
    __shared__ int s_woff[4];
    __shared__ int s_cnt;

    const int tid  = threadIdx.x;
    const int i0   = blockIdx.x * 256 + tid;
    const int wave = tid >> 6;
    const int lane = tid & 63;

    // ---- block-local stream compaction into LDS ----
    const bool fg = (i0 < total) && (fg_mask[i0] != 0);
    const unsigned long long ball = __ballot(fg);
    const int pre = __popcll(ball & ((1ull << lane) - 1ull));
    if (lane == 0) s_wtot[wave] = __popcll(ball);
    __syncthreads();
    if (tid == 0) {
        int off = 0;
        #pragma unroll
        for (int k = 0; k < 4; ++k) { s_woff[k] = off; off += s_wtot[k]; }
        s_cnt = off;
    }
    __syncthreads();
    if (fg) s_idx[s_woff[wave] + pre] = i0;
    __syncthreads();
    const int cnt = s_cnt;

    // ---- cooperative processing: 16 lanes per fg item ----
    float liou = 0.f, ldfl = 0.f;

    const int g  = tid >> 4;   // group 0..15
    const int gl = tid & 15;   // lane within group
    const int q  = gl >> 2;    // side 0..3 (l,t,r,b)
    const int ql = gl & 3;     // lane within quad

    for (int j = g; j < cnt; j += 16) {
        const int i = s_idx[j];
        const int a = i % A_DIM;

        // weight = sum of 80 class scores, split across 16 lanes (20 float4s)
        const float4* ts4 = (const float4*)(target_scores + (size_t)i * 80);
        float4 v = ts4[gl];
        float w = v.x + v.y + v.z + v.w;
        if (gl < 4) { float4 u = ts4[16 + gl]; w += u.x + u.y + u.z + u.w; }
        #pragma unroll
        for (int off = 8; off >= 1; off >>= 1) w += __shfl_xor(w, off);

        const float4 tb = *(const float4*)(target_bboxes + (size_t)i * 4);
        const float ax = anchor_points[2 * a];
        const float ay = anchor_points[2 * a + 1];

        // ---- DFL: quad q owns side q's 16-bin softmax, 4 bins per lane ----
        float tq = (q == 0) ? (ax - tb.x) : (q == 1) ? (ay - tb.y)
                 : (q == 2) ? (tb.z - ax) : (tb.w - ay);
        tq = fminf(fmaxf(tq, 0.f), (float)(REG_MAX - 1) - 0.01f);

        const float4 x4 = ((const float4*)(pred_dist + (size_t)i * 64))[q * 4 + ql];
        float m = fmaxf(fmaxf(x4.x, x4.y), fmaxf(x4.z, x4.w));
        m = fmaxf(m, __shfl_xor(m, 1));
        m = fmaxf(m, __shfl_xor(m, 2));
        float se = __expf(x4.x - m) + __expf(x4.y - m)
                 + __expf(x4.z - m) + __expf(x4.w - m);
        se += __shfl_xor(se, 1);
        se += __shfl_xor(se, 2);
        const float lse = m + __logf(se);

        const int   tl = (int)tq;
        const int   tr = min(tl + 1, REG_MAX - 1);
        const float wl = (float)(tl + 1) - tq;
        const float wr = 1.f - wl;
        const int base = ql * 4;
        float s = 0.f;
        int r = tl - base;
        if (r >= 0 && r < 4) s += wl * (r == 0 ? x4.x : r == 1 ? x4.y : r == 2 ? x4.z : x4.w);
        r = tr - base;
        if (r >= 0 && r < 4) s += wr * (r == 0 ? x4.x : r == 1 ? x4.y : r == 2 ? x4.z : x4.w);
        s += __shfl_xor(s, 1);
        s += __shfl_xor(s, 2);
        if (ql == 0) ldfl += lse - s;   // ce_l*wl + ce_r*wr for this side

        // ---- CIoU on the group leader ----
        if (gl == 0) {
            const float4 pb = *(const float4*)(pred_bboxes + (size_t)i * 4);
            const float x11 = pb.x, y11 = pb.y, x21 = pb.z, y21 = pb.w;
            const float x12 = tb.x, y12 = tb.y, x22 = tb.z, y22 = tb.w;
            const float iw = fmaxf(fminf(x21, x22) - fmaxf(x11, x12), 0.f);
            const float ih = fmaxf(fminf(y21, y22) - fmaxf(y11, y12), 0.f);
            const float inter = iw * ih;
            const float w1 = x21 - x11, h1 = y21 - y11;
            const float w2 = x22 - x12, h2 = y22 - y12;
            const float uni = w1 * h1 + w2 * h2 - inter + EPS;
            const float iou = inter / uni;
            const float cw = fmaxf(x21, x22) - fminf(x11, x12);
            const float ch = fmaxf(y21, y22) - fminf(y11, y12);
            const float c2 = cw * cw + ch * ch + EPS;
            const float dx = x11 + x21 - x12 - x22;
            const float dy = y11 + y21 - y12 - y22;
            const float rho2 = (dx * dx + dy * dy) * 0.25f;
            const float dang = atanf(w1 / (h1 + EPS)) - atanf(w2 / (h2 + EPS));
            const float vv = (4.f / (float)(M_PI * M_PI)) * dang * dang;
            const float alpha = vv / (1.f - iou + vv + EPS);
            const float ciou = iou - (rho2 / c2 + vv * alpha);
            liou += (1.f - ciou) * w;
        }
    }

    // ---- block reduction -> one packed 16B partial store ----
    #pragma unroll
    for (int off = 32; off >= 1; off >>= 1) {
        liou += __shfl_down(liou, off);
        ldfl += __shfl_down(ldfl, off);
    }
    __shared__ float r0[4], r1[4];
    if (lane == 0) { r0[wave] = liou; r1[wave] = ldfl; }
    __syncthreads();
    if (tid == 0) {
        float4 p;
        p.x = r0[0] + r0[1] + r0[2] + r0[3];
        p.y = r1[0] + r1[1] + r1[2] + r1[3];
        p.z = (float)cnt;
        p.w = 0.f;
        partials[blockIdx.x] = p;
    }
}

__global__ __launch_bounds__(256) void bbox_loss_finalize(
    const float4* __restrict__ partials, int nb,
    const float* __restrict__ tss, float* __restrict__ out)
{
    const int tid = threadIdx.x;
    float a = 0.f, b = 0.f, c = 0.f;
    for (int k = tid; k < nb; k += 256) {
        const float4 p = partials[k];
        a += p.x; b += p.y; c += p.z;
    }
    #pragma unroll
    for (int off = 32; off >= 1; off >>= 1) {
        a += __shfl_down(a, off);
        b += __shfl_down(b, off);
        c += __shfl_down(c, off);
    }
    __shared__ float r0[4], r1[4], r2[4];
    const int wave = tid >> 6, lane = tid & 63;
    if (lane == 0) { r0[wave] = a; r1[wave] = b; r2[wave] = c; }
    __syncthreads();
    if (tid == 0) {
        const float A  = r0[0] + r0[1] + r0[2] + r0[3];
        const float Bs = r1[0] + r1[1] + r1[2] + r1[3];
        const float C  = r2[0] + r2[1] + r2[2] + r2[3];
        out[0] = A / tss[0];
        out[1] = Bs / fmaxf(C * 4.f, 1.f);
    }
}

extern "C" void kernel_launch(void* const* d_in, const int* in_sizes, int n_in,
                              void* d_out, int out_size, void* d_ws, size_t ws_size,
                              hipStream_t stream) {
    const float* pred_dist     = (const float*)d_in[0];
    const float* pred_bboxes   = (const float*)d_in[1];
    const float* anchor_points = (const float*)d_in[2];
    const float* target_bboxes = (const float*)d_in[3];
    const float* target_scores = (const float*)d_in[4];
    const float* tss           = (const float*)d_in[5];
    const int*   fg_mask       = (const int*)d_in[6];
    float* out = (float*)d_out;

    float4* partials = (float4*)d_ws;

    const int total = in_sizes[6];               // B*A = 268800
    const int nb = (total + 255) / 256;          // 1050

    bbox_loss_fused<<<nb, 256, 0, stream>>>(pred_dist, pred_bboxes, anchor_points,
                                            target_bboxes, target_scores, fg_mask,
                                            partials, total);
    bbox_loss_finalize<<<1, 256, 0, stream>>>(partials, nb, tss, out);
}